// Round 11
// baseline (715.551 us; speedup 1.0000x reference)
//
#include <hip/hip_runtime.h>

#define U_N 100000
#define I_N 200000
#define D   64
#define NNZ_UI 2000000
#define NNZ_SOC 1000000
#define LN_EPS 1e-5f
#define LSLOPE 0.01f
#define SCAN_CHUNK 1024
#define HCH 8192        // edges per bucket-count/scatter block
#define BSPAN 196       // rows per bucket
#define NB_UI 512
#define NB_UIT 1024
#define NB_SOC 512
#define NBLK_UI 245     // ceil(2M/8192)
#define NBLK_SOC 123    // ceil(1M/8192)

using short8 = __attribute__((ext_vector_type(8))) short;
using f32x4  = __attribute__((ext_vector_type(4))) float;

__device__ __forceinline__ float bf2f(unsigned short h) {
    return __uint_as_float((unsigned int)h << 16);
}
__device__ __forceinline__ unsigned short f2bf(float f) {   // RNE
    unsigned int u = __float_as_uint(f);
    return (unsigned short)((u + 0x7FFFu + ((u >> 16) & 1u)) >> 16);
}

// ---------------------------------------------------------------------------
__global__ void copy2_f4(const float4* __restrict__ src, float4* __restrict__ d1,
                         float4* __restrict__ d2, int n4) {
    int i = blockIdx.x * blockDim.x + threadIdx.x;
    if (i < n4) {
        float4 v = src[i];
        d1[i] = v;
        d2[i] = v;
    }
}

__global__ void wbf_k(const float* __restrict__ wa, const float* __restrict__ wb,
                      unsigned short* __restrict__ dst) {
    int i = blockIdx.x * blockDim.x + threadIdx.x;
    float v = (i < 8192) ? wa[i] : wb[i - 8192];
    dst[i] = f2bf(v);
}

// ---------------------------------------------------------------------------
// Phase A: per-block LDS bucket histogram -> cnt[bucket][block]
struct BCArgs {
    const int4* rows4[3];
    int* cnt[3];
    int nnz[3];
    int nblk[3];
    int nbuck[3];
    int base[4];
};
__global__ __launch_bounds__(256) void bucket_cnt(BCArgs a) {
    __shared__ int lcnt[1024];
    int b = blockIdx.x;
    int si = (b >= a.base[1]) + (b >= a.base[2]);
    int lb = b - a.base[si];
    const int nbuck = a.nbuck[si];
    for (int i = threadIdx.x; i < nbuck; i += 256) lcnt[i] = 0;
    __syncthreads();
    const int be = lb * HCH;
    const int cnt_e = min(HCH, a.nnz[si] - be);
    const int4* r4 = a.rows4[si] + (be >> 2);
    for (int i = threadIdx.x; i < (cnt_e >> 2); i += 256) {
        int4 v = r4[i];
        atomicAdd(&lcnt[v.x / BSPAN], 1);
        atomicAdd(&lcnt[v.y / BSPAN], 1);
        atomicAdd(&lcnt[v.z / BSPAN], 1);
        atomicAdd(&lcnt[v.w / BSPAN], 1);
    }
    __syncthreads();
    int* cnt = a.cnt[si];
    const int nblk = a.nblk[si];
    for (int k = threadIdx.x; k < nbuck; k += 256) cnt[k * nblk + lb] = lcnt[k];
}

// merged 3-section scans -----------------------------------------------------
struct ScanArgs {
    int* cnt[3];
    int n[3];
    int off[3];
    int nb[3];
    int base[4];
};

__global__ __launch_bounds__(256) void scan_p1(ScanArgs a, int* __restrict__ bsum) {
    int b = blockIdx.x;
    int si = (b >= a.base[1]) + (b >= a.base[2]);
    int lb = b - a.base[si];
    const int* cnt = a.cnt[si];
    int n = a.n[si];
    int bs = lb * SCAN_CHUNK + threadIdx.x * 4;
    int s = 0;
    #pragma unroll
    for (int q = 0; q < 4; ++q) {
        int idx = bs + q;
        if (idx < n) s += cnt[idx];
    }
    #pragma unroll
    for (int m = 1; m < 64; m <<= 1) s += __shfl_xor(s, m, 64);
    __shared__ int ws[4];
    if ((threadIdx.x & 63) == 0) ws[threadIdx.x >> 6] = s;
    __syncthreads();
    if (threadIdx.x == 0) bsum[a.off[si] + lb] = ws[0] + ws[1] + ws[2] + ws[3];
}

__global__ __launch_bounds__(256) void scan_p2(ScanArgs a, int* __restrict__ bsum) {
    int si = blockIdx.x;
    int nb = a.nb[si];
    int* bp = bsum + a.off[si];
    int t = threadIdx.x;
    int v = (t < nb) ? bp[t] : 0;
    int lane = t & 63, w = t >> 6;
    int x = v;
    #pragma unroll
    for (int m = 1; m < 64; m <<= 1) {
        int y = __shfl_up(x, m, 64);
        if (lane >= m) x += y;
    }
    __shared__ int wtot[4];
    if (lane == 63) wtot[w] = x;
    __syncthreads();
    int off = 0;
    for (int i = 0; i < w; ++i) off += wtot[i];
    if (t < nb) bp[t] = (x + off) - v;
}

__global__ __launch_bounds__(256) void scan_p3(ScanArgs a, const int* __restrict__ bsum) {
    int b = blockIdx.x;
    int si = (b >= a.base[1]) + (b >= a.base[2]);
    int lb = b - a.base[si];
    int* cnt = a.cnt[si];
    int n = a.n[si];
    int bs = lb * SCAN_CHUNK + threadIdx.x * 4;
    int v[4];
    int s = 0;
    #pragma unroll
    for (int q = 0; q < 4; ++q) {
        int idx = bs + q;
        v[q] = (idx < n) ? cnt[idx] : 0;
        s += v[q];
    }
    int lane = threadIdx.x & 63, w = threadIdx.x >> 6;
    int x = s;
    #pragma unroll
    for (int m = 1; m < 64; m <<= 1) {
        int y = __shfl_up(x, m, 64);
        if (lane >= m) x += y;
    }
    __shared__ int wtot[4];
    if (lane == 63) wtot[w] = x;
    __syncthreads();
    int off = 0;
    for (int i = 0; i < w; ++i) off += wtot[i];
    int run = bsum[a.off[si] + lb] + (x - s) + off;
    #pragma unroll
    for (int q = 0; q < 4; ++q) {
        int idx = bs + q;
        int t = v[q];
        if (idx < n) cnt[idx] = run;
        run += t;
    }
}

// ---------------------------------------------------------------------------
// Phase C: bucket-grouped edge copy; LDS-rank positions, no global atomics.
struct BSArgs {
    const int* rows[3];
    const int* cols[3];
    const float* vals[3];
    const int* cofs[3];
    int2* bkt[3];
    int nnz[3];
    int nblk[3];
    int nbuck[3];
    int base[4];
};
__global__ __launch_bounds__(256) void bucket_scat(BSArgs a) {
    __shared__ int lofs[1024];
    int b = blockIdx.x;
    int si = (b >= a.base[1]) + (b >= a.base[2]);
    int lb = b - a.base[si];
    const int nbuck = a.nbuck[si];
    const int nblk = a.nblk[si];
    const int* cofs = a.cofs[si];
    for (int k = threadIdx.x; k < nbuck; k += 256) lofs[k] = cofs[k * nblk + lb];
    __syncthreads();
    const int be = lb * HCH;
    const int cnt_e = min(HCH, a.nnz[si] - be);
    const int4* r4 = (const int4*)(a.rows[si] + be);
    const int4* c4 = (const int4*)(a.cols[si] + be);
    const float4* v4 = (const float4*)(a.vals[si] + be);
    int2* bkt = a.bkt[si];
    for (int i = threadIdx.x; i < (cnt_e >> 2); i += 256) {
        int4 r = r4[i];
        int4 c = c4[i];
        float4 v = v4[i];
        int k0 = r.x / BSPAN; int p0 = atomicAdd(&lofs[k0], 1);
        bkt[p0] = make_int2((int)((unsigned)c.x | ((unsigned)(r.x - k0 * BSPAN) << 24)),
                            __float_as_int(v.x));
        int k1 = r.y / BSPAN; int p1 = atomicAdd(&lofs[k1], 1);
        bkt[p1] = make_int2((int)((unsigned)c.y | ((unsigned)(r.y - k1 * BSPAN) << 24)),
                            __float_as_int(v.y));
        int k2 = r.z / BSPAN; int p2 = atomicAdd(&lofs[k2], 1);
        bkt[p2] = make_int2((int)((unsigned)c.z | ((unsigned)(r.z - k2 * BSPAN) << 24)),
                            __float_as_int(v.z));
        int k3 = r.w / BSPAN; int p3 = atomicAdd(&lofs[k3], 1);
        bkt[p3] = make_int2((int)((unsigned)c.w | ((unsigned)(r.w - k3 * BSPAN) << 24)),
                            __float_as_int(v.w));
    }
}

// ---------------------------------------------------------------------------
// Phase D: per-bucket CSR finalize.
struct BDArgs {
    const int* cofs[3];
    const int2* bkt[3];
    int2* pairs[3];
    int* rp[3];
    int nnz[3];
    int nblk[3];
    int nbuck[3];
    int nrows[3];
    int base[4];
};
__global__ __launch_bounds__(256) void bucket_csr(BDArgs a) {
    __shared__ int lcnt[BSPAN];
    __shared__ int lrun[BSPAN];
    __shared__ int wt[4];
    int b = blockIdx.x;
    int si = (b >= a.base[1]) + (b >= a.base[2]);
    int k = b - a.base[si];
    const int nblk = a.nblk[si];
    const int* cofs = a.cofs[si];
    const int base_p = cofs[k * nblk];
    const int end_p = (k == a.nbuck[si] - 1) ? a.nnz[si] : cofs[(k + 1) * nblk];
    const int2* bkt = a.bkt[si];
    const int tid = threadIdx.x;
    if (tid < BSPAN) lcnt[tid] = 0;
    __syncthreads();
    for (int e = base_p + tid; e < end_p; e += 256)
        atomicAdd(&lcnt[(unsigned)bkt[e].x >> 24], 1);
    __syncthreads();
    int v = (tid < BSPAN) ? lcnt[tid] : 0;
    int lane = tid & 63, w = tid >> 6;
    int x = v;
    #pragma unroll
    for (int m = 1; m < 64; m <<= 1) {
        int y = __shfl_up(x, m, 64);
        if (lane >= m) x += y;
    }
    if (lane == 63) wt[w] = x;
    __syncthreads();
    int off = 0;
    for (int i = 0; i < w; ++i) off += wt[i];
    int excl = x + off - v;
    const int row0 = k * BSPAN;
    if (tid < BSPAN) {
        lrun[tid] = excl;
        if (row0 + tid < a.nrows[si]) a.rp[si][row0 + tid] = base_p + excl;
    }
    __syncthreads();
    int2* pairs = a.pairs[si];
    for (int e = base_p + tid; e < end_p; e += 256) {
        int2 q = bkt[e];
        int lr = (int)((unsigned)q.x >> 24);
        int pos = base_p + atomicAdd(&lrun[lr], 1);
        pairs[pos] = make_int2(q.x & 0xFFFFFF, q.y);
    }
}

// ---------------------------------------------------------------------------
// MFMA transform: dst_bf16[n,64] = src_f32[n,64] @ W^T
struct XfArgs {
    const float* src[3];
    const unsigned short* wbf[3];
    unsigned short* dst[3];
    int n[3];
    int base[4];
};
__global__ __launch_bounds__(256) void xform_mfma(XfArgs a) {
    int b = blockIdx.x;
    int si = (b >= a.base[1]) + (b >= a.base[2]);
    const float* src = a.src[si];
    const unsigned short* wb = a.wbf[si];
    unsigned short* dst = a.dst[si];
    const int n = a.n[si];

    const int lane = threadIdx.x & 63;
    const int wv   = threadIdx.x >> 6;
    const int rbw  = (b - a.base[si]) * 64 + wv * 16;
    const int m = lane & 15, g = lane >> 4;

    f32x4 acc0 = {0.f, 0.f, 0.f, 0.f};
    f32x4 acc1 = acc0, acc2 = acc0, acc3 = acc0;

    const int arow = min(rbw + m, n - 1);
    const float* xp = src + (size_t)arow * D + g * 8;
    const unsigned short* wp0 = wb + (size_t)m * D + g * 8;

    #pragma unroll
    for (int t = 0; t < 2; ++t) {
        float4 a0 = *(const float4*)(xp + t * 32);
        float4 a1 = *(const float4*)(xp + t * 32 + 4);
        short8 af;
        af[0] = (short)f2bf(a0.x); af[1] = (short)f2bf(a0.y);
        af[2] = (short)f2bf(a0.z); af[3] = (short)f2bf(a0.w);
        af[4] = (short)f2bf(a1.x); af[5] = (short)f2bf(a1.y);
        af[6] = (short)f2bf(a1.z); af[7] = (short)f2bf(a1.w);
        const unsigned short* wp = wp0 + t * 32;
        short8 b0 = *(const short8*)(wp);
        short8 b1 = *(const short8*)(wp + 16 * D);
        short8 b2 = *(const short8*)(wp + 32 * D);
        short8 b3 = *(const short8*)(wp + 48 * D);
        acc0 = __builtin_amdgcn_mfma_f32_16x16x32_bf16(af, b0, acc0, 0, 0, 0);
        acc1 = __builtin_amdgcn_mfma_f32_16x16x32_bf16(af, b1, acc1, 0, 0, 0);
        acc2 = __builtin_amdgcn_mfma_f32_16x16x32_bf16(af, b2, acc2, 0, 0, 0);
        acc3 = __builtin_amdgcn_mfma_f32_16x16x32_bf16(af, b3, acc3, 0, 0, 0);
    }

    #pragma unroll
    for (int reg = 0; reg < 4; ++reg) {
        int orow = rbw + g * 4 + reg;
        if (orow < n) {
            size_t o = (size_t)orow * D + m;
            dst[o]      = f2bf(acc0[reg]);
            dst[o + 16] = f2bf(acc1[reg]);
            dst[o + 32] = f2bf(acc2[reg]);
            dst[o + 48] = f2bf(acc3[reg]);
        }
    }
}

// ---------------------------------------------------------------------------
// SpMM + epilogue, wave-per-row. Block = 1024 thr = 16 waves = 16 rows.
// Wave: 4 edge-slots x 16 lanes; cross-slot shfl reduce; LN on lanes<16.
// NEXT: MFMA epilogue computing Ynext = LNout @ Wnext^T for the 16 rows.
struct SpArgs {
    const int* rptr[3];
    const int2* pairs[3];
    const unsigned short* y[3];
    const float* cur[3];
    const float* bias[3];
    const float* gamma[3];
    const float* beta[3];
    float* dst[3];
    const unsigned short* wnext[3];
    unsigned short* ynext[3];
    int n[3];
    int nnzc[3];
    int base[4];
};
template<int NEXT>
__global__ __launch_bounds__(1024) void spmm_ln(SpArgs a) {
    __shared__ float lno[16][68];   // 16 rows x 64 f32, stride 68 (bank-friendly)
    int b = blockIdx.x;
    int si = (b >= a.base[1]) + (b >= a.base[2]);
    const int lb = b - a.base[si];
    const int wv   = threadIdx.x >> 6;    // row within block (0..15)
    const int lane = threadIdx.x & 63;
    const int slot = lane >> 4, sub = lane & 15;
    const int row  = lb * 16 + wv;

    const int* rptr = a.rptr[si];
    const int2* pairs = a.pairs[si];
    const unsigned short* y = a.y[si];

    const int start = rptr[row];
    const int end   = (row == a.n[si] - 1) ? a.nnzc[si] : rptr[row + 1];

    float4 acc = make_float4(0.f, 0.f, 0.f, 0.f);
    int e = start + slot;
    for (; e + 4 < end; e += 8) {
        int2 p0 = pairs[e];
        int2 p1 = pairs[e + 4];
        float v0 = __int_as_float(p0.y);
        float v1 = __int_as_float(p1.y);
        ushort4 q0 = *(const ushort4*)(y + (size_t)p0.x * D + sub * 4);
        ushort4 q1 = *(const ushort4*)(y + (size_t)p1.x * D + sub * 4);
        acc.x += v0 * bf2f(q0.x); acc.y += v0 * bf2f(q0.y);
        acc.z += v0 * bf2f(q0.z); acc.w += v0 * bf2f(q0.w);
        acc.x += v1 * bf2f(q1.x); acc.y += v1 * bf2f(q1.y);
        acc.z += v1 * bf2f(q1.z); acc.w += v1 * bf2f(q1.w);
    }
    if (e < end) {
        int2 p0 = pairs[e];
        float v0 = __int_as_float(p0.y);
        ushort4 q0 = *(const ushort4*)(y + (size_t)p0.x * D + sub * 4);
        acc.x += v0 * bf2f(q0.x); acc.y += v0 * bf2f(q0.y);
        acc.z += v0 * bf2f(q0.z); acc.w += v0 * bf2f(q0.w);
    }
    // reduce across the 4 slots (after this, all lanes hold the slot-sum)
    #pragma unroll
    for (int m = 16; m < 64; m <<= 1) {
        acc.x += __shfl_xor(acc.x, m, 64);
        acc.y += __shfl_xor(acc.y, m, 64);
        acc.z += __shfl_xor(acc.z, m, 64);
        acc.w += __shfl_xor(acc.w, m, 64);
    }

    if (lane < 16) {
        float4 bi = *(const float4*)(a.bias[si] + sub * 4);
        float4 h;
        h.x = acc.x + bi.x; h.y = acc.y + bi.y; h.z = acc.z + bi.z; h.w = acc.w + bi.w;
        h.x = h.x > 0.f ? h.x : LSLOPE * h.x;
        h.y = h.y > 0.f ? h.y : LSLOPE * h.y;
        h.z = h.z > 0.f ? h.z : LSLOPE * h.z;
        h.w = h.w > 0.f ? h.w : LSLOPE * h.w;
        float4 cu = *(const float4*)(a.cur[si] + (size_t)row * D + sub * 4);
        float4 x;
        x.x = cu.x + h.x; x.y = cu.y + h.y; x.z = cu.z + h.z; x.w = cu.w + h.w;

        float s  = x.x + x.y + x.z + x.w;
        float s2 = x.x * x.x + x.y * x.y + x.z * x.z + x.w * x.w;
        #pragma unroll
        for (int m = 8; m >= 1; m >>= 1) {
            s  += __shfl_xor(s, m, 64);
            s2 += __shfl_xor(s2, m, 64);
        }
        float mean = s * (1.f / 64.f);
        float var  = s2 * (1.f / 64.f) - mean * mean;
        float rstd = rsqrtf(var + LN_EPS);

        float4 g4  = *(const float4*)(a.gamma[si] + sub * 4);
        float4 be4 = *(const float4*)(a.beta[si]  + sub * 4);
        float4 o;
        o.x = (x.x - mean) * rstd * g4.x + be4.x;
        o.y = (x.y - mean) * rstd * g4.y + be4.y;
        o.z = (x.z - mean) * rstd * g4.z + be4.z;
        o.w = (x.w - mean) * rstd * g4.w + be4.w;
        *(float4*)(a.dst[si] + (size_t)row * D + sub * 4) = o;
        if (NEXT) *(float4*)&lno[wv][sub * 4] = o;
    }

    if (NEXT) {
        __syncthreads();
        if (wv < 4) {   // wave wv computes output cols wv*16..wv*16+15
            const unsigned short* wn = a.wnext[si];
            unsigned short* yn = a.ynext[si] + (size_t)(lb * 16) * D;
            const int m = lane & 15, g = lane >> 4;
            f32x4 c = {0.f, 0.f, 0.f, 0.f};
            #pragma unroll
            for (int t = 0; t < 2; ++t) {
                float4 a0 = *(const float4*)&lno[m][t * 32 + g * 8];
                float4 a1 = *(const float4*)&lno[m][t * 32 + g * 8 + 4];
                short8 af;
                af[0] = (short)f2bf(a0.x); af[1] = (short)f2bf(a0.y);
                af[2] = (short)f2bf(a0.z); af[3] = (short)f2bf(a0.w);
                af[4] = (short)f2bf(a1.x); af[5] = (short)f2bf(a1.y);
                af[6] = (short)f2bf(a1.z); af[7] = (short)f2bf(a1.w);
                short8 bf = *(const short8*)(wn + (size_t)(wv * 16 + m) * D + t * 32 + g * 8);
                c = __builtin_amdgcn_mfma_f32_16x16x32_bf16(af, bf, c, 0, 0, 0);
            }
            #pragma unroll
            for (int reg = 0; reg < 4; ++reg)
                yn[(size_t)(g * 4 + reg) * D + wv * 16 + m] = f2bf(c[reg]);
        }
    }
}

// ---------------------------------------------------------------------------
extern "C" void kernel_launch(void* const* d_in, const int* in_sizes, int n_in,
                              void* d_out, int out_size, void* d_ws, size_t ws_size,
                              hipStream_t stream)
{
    const float* user_emb = (const float*)d_in[0];
    const float* item_emb = (const float*)d_in[1];
    const int*   ui_rows  = (const int*)d_in[2];
    const int*   ui_cols  = (const int*)d_in[3];
    const float* ui_vals  = (const float*)d_in[4];
    const int*   soc_rows = (const int*)d_in[5];
    const int*   soc_cols = (const int*)d_in[6];
    const float* soc_vals = (const float*)d_in[7];
    const float* ui_W     = (const float*)d_in[8];
    const float* ui_b     = (const float*)d_in[9];
    const float* soc_W    = (const float*)d_in[10];
    const float* soc_b    = (const float*)d_in[11];
    const float* ln_ui_g  = (const float*)d_in[12];
    const float* ln_ui_b  = (const float*)d_in[13];
    const float* ln_soc_g = (const float*)d_in[14];
    const float* ln_soc_b = (const float*)d_in[15];

    float* out = (float*)d_out;
    const size_t UD = (size_t)U_N * D;
    const size_t ID = (size_t)I_N * D;

    float* o_ui0 = out;
    float* o_ui1 = out + UD;
    float* o_ui2 = out + 2 * UD;
    float* o_s0  = out + 3 * UD;
    float* o_s1  = out + 4 * UD;
    float* o_s2  = out + 5 * UD;
    float* o_ci  = out + 6 * UD;

    // workspace layout
    int2* pairs_ui  = (int2*)d_ws;
    int2* pairs_uiT = pairs_ui + NNZ_UI;
    int2* pairs_soc = pairs_uiT + NNZ_UI;
    int*  rp_ui     = (int*)(pairs_soc + NNZ_SOC);
    int*  rp_uiT    = rp_ui + U_N;
    int*  rp_soc    = rp_uiT + I_N;
    int*  bsum      = rp_soc + U_N;
    unsigned short* wbf = (unsigned short*)(bsum + 512);
    unsigned short* Yi  = wbf + 16384;   // I*D bf16
    unsigned short* Yu  = Yi + ID;       // U*D
    unsigned short* Ys  = Yu + UD;       // U*D
    unsigned short* Yi2 = Ys + UD;       // second Y set (fused path only)
    unsigned short* Yu2 = Yi2 + ID;
    unsigned short* Ys2 = Yu2 + UD;
    // bucket copy + count matrices overlap the first Y region (dead before T0)
    int2* bkt_ui  = (int2*)Yi;
    int2* bkt_uiT = bkt_ui + NNZ_UI;
    int2* bkt_soc = bkt_uiT + NNZ_UI;
    int*  cnt_ui  = (int*)(bkt_soc + NNZ_SOC);
    int*  cnt_uiT = cnt_ui + NB_UI * NBLK_UI;
    int*  cnt_soc = cnt_uiT + NB_UIT * NBLK_UI;

    const unsigned short* wbfUI0 = wbf;
    const unsigned short* wbfUI1 = wbf + 4096;
    const unsigned short* wbfS0  = wbf + 8192;
    const unsigned short* wbfS1  = wbf + 12288;

    const bool fused = ws_size >= (size_t)((char*)(Ys2 + UD) - (char*)d_ws);

    const int nthr = 256;

    // 1) weights to bf16
    wbf_k<<<64, nthr, 0, stream>>>(ui_W, soc_W, wbf);

    // 2) Phase A: bucket counts
    {
        BCArgs ba;
        ba.rows4[0] = (const int4*)ui_rows;  ba.cnt[0] = cnt_ui;  ba.nnz[0] = NNZ_UI;
        ba.nblk[0] = NBLK_UI;  ba.nbuck[0] = NB_UI;
        ba.rows4[1] = (const int4*)ui_cols;  ba.cnt[1] = cnt_uiT; ba.nnz[1] = NNZ_UI;
        ba.nblk[1] = NBLK_UI;  ba.nbuck[1] = NB_UIT;
        ba.rows4[2] = (const int4*)soc_rows; ba.cnt[2] = cnt_soc; ba.nnz[2] = NNZ_SOC;
        ba.nblk[2] = NBLK_SOC; ba.nbuck[2] = NB_SOC;
        ba.base[0] = 0; ba.base[1] = NBLK_UI; ba.base[2] = 2 * NBLK_UI;
        ba.base[3] = 2 * NBLK_UI + NBLK_SOC;
        bucket_cnt<<<ba.base[3], nthr, 0, stream>>>(ba);
    }

    // 3) Phase B: scans
    {
        ScanArgs sa;
        sa.cnt[0] = cnt_ui;  sa.n[0] = NB_UI * NBLK_UI;
        sa.cnt[1] = cnt_uiT; sa.n[1] = NB_UIT * NBLK_UI;
        sa.cnt[2] = cnt_soc; sa.n[2] = NB_SOC * NBLK_SOC;
        int nb0 = (sa.n[0] + SCAN_CHUNK - 1) / SCAN_CHUNK;
        int nb1 = (sa.n[1] + SCAN_CHUNK - 1) / SCAN_CHUNK;
        int nb2 = (sa.n[2] + SCAN_CHUNK - 1) / SCAN_CHUNK;
        sa.nb[0] = nb0; sa.nb[1] = nb1; sa.nb[2] = nb2;
        sa.off[0] = 0; sa.off[1] = nb0; sa.off[2] = nb0 + nb1;
        sa.base[0] = 0; sa.base[1] = nb0; sa.base[2] = nb0 + nb1; sa.base[3] = nb0 + nb1 + nb2;
        scan_p1<<<sa.base[3], nthr, 0, stream>>>(sa, bsum);
        scan_p2<<<3, nthr, 0, stream>>>(sa, bsum);
        scan_p3<<<sa.base[3], nthr, 0, stream>>>(sa, bsum);
    }

    // 4) Phase C: bucket-grouped edge copy
    {
        BSArgs ca;
        ca.rows[0] = ui_rows;  ca.cols[0] = ui_cols;  ca.vals[0] = ui_vals;
        ca.cofs[0] = cnt_ui;  ca.bkt[0] = bkt_ui;  ca.nnz[0] = NNZ_UI;
        ca.nblk[0] = NBLK_UI;  ca.nbuck[0] = NB_UI;
        ca.rows[1] = ui_cols;  ca.cols[1] = ui_rows;  ca.vals[1] = ui_vals;
        ca.cofs[1] = cnt_uiT; ca.bkt[1] = bkt_uiT; ca.nnz[1] = NNZ_UI;
        ca.nblk[1] = NBLK_UI;  ca.nbuck[1] = NB_UIT;
        ca.rows[2] = soc_rows; ca.cols[2] = soc_cols; ca.vals[2] = soc_vals;
        ca.cofs[2] = cnt_soc; ca.bkt[2] = bkt_soc; ca.nnz[2] = NNZ_SOC;
        ca.nblk[2] = NBLK_SOC; ca.nbuck[2] = NB_SOC;
        ca.base[0] = 0; ca.base[1] = NBLK_UI; ca.base[2] = 2 * NBLK_UI;
        ca.base[3] = 2 * NBLK_UI + NBLK_SOC;
        bucket_scat<<<ca.base[3], nthr, 0, stream>>>(ca);
    }

    // 5) copy user_emb to output slots
    copy2_f4<<<(int)(UD / 4 + nthr - 1) / nthr, nthr, 0, stream>>>(
        (const float4*)user_emb, (float4*)o_ui0, (float4*)o_s0, (int)(UD / 4));

    // 6) Phase D: per-bucket CSR finalize
    {
        BDArgs da;
        da.cofs[0] = cnt_ui;  da.bkt[0] = bkt_ui;  da.pairs[0] = pairs_ui;  da.rp[0] = rp_ui;
        da.nnz[0] = NNZ_UI;  da.nblk[0] = NBLK_UI;  da.nbuck[0] = NB_UI;  da.nrows[0] = U_N;
        da.cofs[1] = cnt_uiT; da.bkt[1] = bkt_uiT; da.pairs[1] = pairs_uiT; da.rp[1] = rp_uiT;
        da.nnz[1] = NNZ_UI;  da.nblk[1] = NBLK_UI;  da.nbuck[1] = NB_UIT; da.nrows[1] = I_N;
        da.cofs[2] = cnt_soc; da.bkt[2] = bkt_soc; da.pairs[2] = pairs_soc; da.rp[2] = rp_soc;
        da.nnz[2] = NNZ_SOC; da.nblk[2] = NBLK_SOC; da.nbuck[2] = NB_SOC;  da.nrows[2] = U_N;
        da.base[0] = 0; da.base[1] = NB_UI; da.base[2] = NB_UI + NB_UIT;
        da.base[3] = NB_UI + NB_UIT + NB_SOC;
        bucket_csr<<<da.base[3], nthr, 0, stream>>>(da);
    }

    const int xb_i = (I_N + 63) / 64;
    const int xb_u = (U_N + 63) / 64;

    // 7) T0: layer-0 transforms of raw embeddings
    {
        XfArgs xa;
        xa.src[0] = item_emb; xa.wbf[0] = wbfUI0; xa.dst[0] = Yi; xa.n[0] = I_N;
        xa.src[1] = user_emb; xa.wbf[1] = wbfUI0; xa.dst[1] = Yu; xa.n[1] = U_N;
        xa.src[2] = user_emb; xa.wbf[2] = wbfS0;  xa.dst[2] = Ys; xa.n[2] = U_N;
        xa.base[0] = 0; xa.base[1] = xb_i; xa.base[2] = xb_i + xb_u; xa.base[3] = xb_i + 2 * xb_u;
        xform_mfma<<<xa.base[3], nthr, 0, stream>>>(xa);
    }

    // common SpArgs skeleton
    SpArgs p0;
    p0.rptr[0] = rp_ui;  p0.pairs[0] = pairs_ui;  p0.y[0] = Yi; p0.cur[0] = user_emb;
    p0.bias[0] = ui_b;  p0.gamma[0] = ln_ui_g;  p0.beta[0] = ln_ui_b;  p0.dst[0] = o_ui1;
    p0.n[0] = U_N; p0.nnzc[0] = NNZ_UI;
    p0.rptr[1] = rp_uiT; p0.pairs[1] = pairs_uiT; p0.y[1] = Yu; p0.cur[1] = item_emb;
    p0.bias[1] = ui_b;  p0.gamma[1] = ln_ui_g;  p0.beta[1] = ln_ui_b;  p0.dst[1] = o_ci;
    p0.n[1] = I_N; p0.nnzc[1] = NNZ_UI;
    p0.rptr[2] = rp_soc; p0.pairs[2] = pairs_soc; p0.y[2] = Ys; p0.cur[2] = user_emb;
    p0.bias[2] = soc_b; p0.gamma[2] = ln_soc_g; p0.beta[2] = ln_soc_b; p0.dst[2] = o_s1;
    p0.n[2] = U_N; p0.nnzc[2] = NNZ_SOC;
    p0.base[0] = 0; p0.base[1] = U_N / 16; p0.base[2] = U_N / 16 + I_N / 16;
    p0.base[3] = 2 * (U_N / 16) + I_N / 16;
    p0.wnext[0] = nullptr; p0.wnext[1] = nullptr; p0.wnext[2] = nullptr;
    p0.ynext[0] = nullptr; p0.ynext[1] = nullptr; p0.ynext[2] = nullptr;

    SpArgs p1 = p0;
    p1.bias[0] = ui_b + 64;  p1.gamma[0] = ln_ui_g + 64;  p1.beta[0] = ln_ui_b + 64;
    p1.bias[1] = ui_b + 64;  p1.gamma[1] = ln_ui_g + 64;  p1.beta[1] = ln_ui_b + 64;
    p1.bias[2] = soc_b + 64; p1.gamma[2] = ln_soc_g + 64; p1.beta[2] = ln_soc_b + 64;
    p1.cur[0] = o_ui1; p1.dst[0] = o_ui2;
    p1.cur[1] = o_ci;  p1.dst[1] = o_ci;   // in-place: row read then written by same wave
    p1.cur[2] = o_s1;  p1.dst[2] = o_s2;

    if (fused) {
        // 8) spmm L0 with fused next-layer transform:
        //    sec0 outputs users -> Yu2; sec1 outputs items -> Yi2; sec2 -> Ys2
        p0.wnext[0] = wbfUI1; p0.ynext[0] = Yu2;
        p0.wnext[1] = wbfUI1; p0.ynext[1] = Yi2;
        p0.wnext[2] = wbfS1;  p0.ynext[2] = Ys2;
        spmm_ln<1><<<p0.base[3], 1024, 0, stream>>>(p0);

        // 9) spmm L1 gathers from second Y set
        p1.y[0] = Yi2; p1.y[1] = Yu2; p1.y[2] = Ys2;
        spmm_ln<0><<<p1.base[3], 1024, 0, stream>>>(p1);
    } else {
        // fallback: round-10 sequence (separate T1)
        spmm_ln<0><<<p0.base[3], 1024, 0, stream>>>(p0);
        {
            XfArgs xa;
            xa.src[0] = o_ci;  xa.wbf[0] = wbfUI1; xa.dst[0] = Yi; xa.n[0] = I_N;
            xa.src[1] = o_ui1; xa.wbf[1] = wbfUI1; xa.dst[1] = Yu; xa.n[1] = U_N;
            xa.src[2] = o_s1;  xa.wbf[2] = wbfS1;  xa.dst[2] = Ys; xa.n[2] = U_N;
            xa.base[0] = 0; xa.base[1] = xb_i; xa.base[2] = xb_i + xb_u;
            xa.base[3] = xb_i + 2 * xb_u;
            xform_mfma<<<xa.base[3], nthr, 0, stream>>>(xa);
        }
        spmm_ln<0><<<p1.base[3], 1024, 0, stream>>>(p1);
    }
}

// Round 12
// 494.729 us; speedup vs baseline: 1.4463x; 1.4463x over previous
//
#include <hip/hip_runtime.h>

#define U_N 100000
#define I_N 200000
#define D   64
#define NNZ_UI 2000000
#define NNZ_SOC 1000000
#define LN_EPS 1e-5f
#define LSLOPE 0.01f
#define SCAN_CHUNK 1024
#define HCH 8192        // edges per bucket-count/scatter block
#define BSPAN 196       // rows per bucket
#define NB_UI 512
#define NB_UIT 1024
#define NB_SOC 512
#define NBLK_UI 245     // ceil(2M/8192)
#define NBLK_SOC 123    // ceil(1M/8192)

using short8 = __attribute__((ext_vector_type(8))) short;
using f32x4  = __attribute__((ext_vector_type(4))) float;

__device__ __forceinline__ float bf2f(unsigned short h) {
    return __uint_as_float((unsigned int)h << 16);
}
__device__ __forceinline__ unsigned short f2bf(float f) {   // RNE
    unsigned int u = __float_as_uint(f);
    return (unsigned short)((u + 0x7FFFu + ((u >> 16) & 1u)) >> 16);
}

// ---------------------------------------------------------------------------
__global__ void copy2_f4(const float4* __restrict__ src, float4* __restrict__ d1,
                         float4* __restrict__ d2, int n4) {
    int i = blockIdx.x * blockDim.x + threadIdx.x;
    if (i < n4) {
        float4 v = src[i];
        d1[i] = v;
        d2[i] = v;
    }
}

__global__ void wbf_k(const float* __restrict__ wa, const float* __restrict__ wb,
                      unsigned short* __restrict__ dst) {
    int i = blockIdx.x * blockDim.x + threadIdx.x;
    float v = (i < 8192) ? wa[i] : wb[i - 8192];
    dst[i] = f2bf(v);
}

// ---------------------------------------------------------------------------
// Phase A: per-block LDS bucket histogram -> cnt[bucket][block]
struct BCArgs {
    const int4* rows4[3];
    int* cnt[3];
    int nnz[3];
    int nblk[3];
    int nbuck[3];
    int base[4];
};
__global__ __launch_bounds__(256) void bucket_cnt(BCArgs a) {
    __shared__ int lcnt[1024];
    int b = blockIdx.x;
    int si = (b >= a.base[1]) + (b >= a.base[2]);
    int lb = b - a.base[si];
    const int nbuck = a.nbuck[si];
    for (int i = threadIdx.x; i < nbuck; i += 256) lcnt[i] = 0;
    __syncthreads();
    const int be = lb * HCH;
    const int cnt_e = min(HCH, a.nnz[si] - be);
    const int4* r4 = a.rows4[si] + (be >> 2);
    for (int i = threadIdx.x; i < (cnt_e >> 2); i += 256) {
        int4 v = r4[i];
        atomicAdd(&lcnt[v.x / BSPAN], 1);
        atomicAdd(&lcnt[v.y / BSPAN], 1);
        atomicAdd(&lcnt[v.z / BSPAN], 1);
        atomicAdd(&lcnt[v.w / BSPAN], 1);
    }
    __syncthreads();
    int* cnt = a.cnt[si];
    const int nblk = a.nblk[si];
    for (int k = threadIdx.x; k < nbuck; k += 256) cnt[k * nblk + lb] = lcnt[k];
}

// merged 3-section scans -----------------------------------------------------
struct ScanArgs {
    int* cnt[3];
    int n[3];
    int off[3];
    int nb[3];
    int base[4];
};

__global__ __launch_bounds__(256) void scan_p1(ScanArgs a, int* __restrict__ bsum) {
    int b = blockIdx.x;
    int si = (b >= a.base[1]) + (b >= a.base[2]);
    int lb = b - a.base[si];
    const int* cnt = a.cnt[si];
    int n = a.n[si];
    int bs = lb * SCAN_CHUNK + threadIdx.x * 4;
    int s = 0;
    #pragma unroll
    for (int q = 0; q < 4; ++q) {
        int idx = bs + q;
        if (idx < n) s += cnt[idx];
    }
    #pragma unroll
    for (int m = 1; m < 64; m <<= 1) s += __shfl_xor(s, m, 64);
    __shared__ int ws[4];
    if ((threadIdx.x & 63) == 0) ws[threadIdx.x >> 6] = s;
    __syncthreads();
    if (threadIdx.x == 0) bsum[a.off[si] + lb] = ws[0] + ws[1] + ws[2] + ws[3];
}

__global__ __launch_bounds__(256) void scan_p2(ScanArgs a, int* __restrict__ bsum) {
    int si = blockIdx.x;
    int nb = a.nb[si];
    int* bp = bsum + a.off[si];
    int t = threadIdx.x;
    int v = (t < nb) ? bp[t] : 0;
    int lane = t & 63, w = t >> 6;
    int x = v;
    #pragma unroll
    for (int m = 1; m < 64; m <<= 1) {
        int y = __shfl_up(x, m, 64);
        if (lane >= m) x += y;
    }
    __shared__ int wtot[4];
    if (lane == 63) wtot[w] = x;
    __syncthreads();
    int off = 0;
    for (int i = 0; i < w; ++i) off += wtot[i];
    if (t < nb) bp[t] = (x + off) - v;
}

__global__ __launch_bounds__(256) void scan_p3(ScanArgs a, const int* __restrict__ bsum) {
    int b = blockIdx.x;
    int si = (b >= a.base[1]) + (b >= a.base[2]);
    int lb = b - a.base[si];
    int* cnt = a.cnt[si];
    int n = a.n[si];
    int bs = lb * SCAN_CHUNK + threadIdx.x * 4;
    int v[4];
    int s = 0;
    #pragma unroll
    for (int q = 0; q < 4; ++q) {
        int idx = bs + q;
        v[q] = (idx < n) ? cnt[idx] : 0;
        s += v[q];
    }
    int lane = threadIdx.x & 63, w = threadIdx.x >> 6;
    int x = s;
    #pragma unroll
    for (int m = 1; m < 64; m <<= 1) {
        int y = __shfl_up(x, m, 64);
        if (lane >= m) x += y;
    }
    __shared__ int wtot[4];
    if (lane == 63) wtot[w] = x;
    __syncthreads();
    int off = 0;
    for (int i = 0; i < w; ++i) off += wtot[i];
    int run = bsum[a.off[si] + lb] + (x - s) + off;
    #pragma unroll
    for (int q = 0; q < 4; ++q) {
        int idx = bs + q;
        int t = v[q];
        if (idx < n) cnt[idx] = run;
        run += t;
    }
}

// ---------------------------------------------------------------------------
// Phase C: bucket-grouped edge copy; LDS-rank positions, no global atomics.
struct BSArgs {
    const int* rows[3];
    const int* cols[3];
    const float* vals[3];
    const int* cofs[3];
    int2* bkt[3];
    int nnz[3];
    int nblk[3];
    int nbuck[3];
    int base[4];
};
__global__ __launch_bounds__(256) void bucket_scat(BSArgs a) {
    __shared__ int lofs[1024];
    int b = blockIdx.x;
    int si = (b >= a.base[1]) + (b >= a.base[2]);
    int lb = b - a.base[si];
    const int nbuck = a.nbuck[si];
    const int nblk = a.nblk[si];
    const int* cofs = a.cofs[si];
    for (int k = threadIdx.x; k < nbuck; k += 256) lofs[k] = cofs[k * nblk + lb];
    __syncthreads();
    const int be = lb * HCH;
    const int cnt_e = min(HCH, a.nnz[si] - be);
    const int4* r4 = (const int4*)(a.rows[si] + be);
    const int4* c4 = (const int4*)(a.cols[si] + be);
    const float4* v4 = (const float4*)(a.vals[si] + be);
    int2* bkt = a.bkt[si];
    for (int i = threadIdx.x; i < (cnt_e >> 2); i += 256) {
        int4 r = r4[i];
        int4 c = c4[i];
        float4 v = v4[i];
        int k0 = r.x / BSPAN; int p0 = atomicAdd(&lofs[k0], 1);
        bkt[p0] = make_int2((int)((unsigned)c.x | ((unsigned)(r.x - k0 * BSPAN) << 24)),
                            __float_as_int(v.x));
        int k1 = r.y / BSPAN; int p1 = atomicAdd(&lofs[k1], 1);
        bkt[p1] = make_int2((int)((unsigned)c.y | ((unsigned)(r.y - k1 * BSPAN) << 24)),
                            __float_as_int(v.y));
        int k2 = r.z / BSPAN; int p2 = atomicAdd(&lofs[k2], 1);
        bkt[p2] = make_int2((int)((unsigned)c.z | ((unsigned)(r.z - k2 * BSPAN) << 24)),
                            __float_as_int(v.z));
        int k3 = r.w / BSPAN; int p3 = atomicAdd(&lofs[k3], 1);
        bkt[p3] = make_int2((int)((unsigned)c.w | ((unsigned)(r.w - k3 * BSPAN) << 24)),
                            __float_as_int(v.w));
    }
}

// ---------------------------------------------------------------------------
// Phase D: per-bucket CSR finalize.
struct BDArgs {
    const int* cofs[3];
    const int2* bkt[3];
    int2* pairs[3];
    int* rp[3];
    int nnz[3];
    int nblk[3];
    int nbuck[3];
    int nrows[3];
    int base[4];
};
__global__ __launch_bounds__(256) void bucket_csr(BDArgs a) {
    __shared__ int lcnt[BSPAN];
    __shared__ int lrun[BSPAN];
    __shared__ int wt[4];
    int b = blockIdx.x;
    int si = (b >= a.base[1]) + (b >= a.base[2]);
    int k = b - a.base[si];
    const int nblk = a.nblk[si];
    const int* cofs = a.cofs[si];
    const int base_p = cofs[k * nblk];
    const int end_p = (k == a.nbuck[si] - 1) ? a.nnz[si] : cofs[(k + 1) * nblk];
    const int2* bkt = a.bkt[si];
    const int tid = threadIdx.x;
    if (tid < BSPAN) lcnt[tid] = 0;
    __syncthreads();
    for (int e = base_p + tid; e < end_p; e += 256)
        atomicAdd(&lcnt[(unsigned)bkt[e].x >> 24], 1);
    __syncthreads();
    int v = (tid < BSPAN) ? lcnt[tid] : 0;
    int lane = tid & 63, w = tid >> 6;
    int x = v;
    #pragma unroll
    for (int m = 1; m < 64; m <<= 1) {
        int y = __shfl_up(x, m, 64);
        if (lane >= m) x += y;
    }
    if (lane == 63) wt[w] = x;
    __syncthreads();
    int off = 0;
    for (int i = 0; i < w; ++i) off += wt[i];
    int excl = x + off - v;
    const int row0 = k * BSPAN;
    if (tid < BSPAN) {
        lrun[tid] = excl;
        if (row0 + tid < a.nrows[si]) a.rp[si][row0 + tid] = base_p + excl;
    }
    __syncthreads();
    int2* pairs = a.pairs[si];
    for (int e = base_p + tid; e < end_p; e += 256) {
        int2 q = bkt[e];
        int lr = (int)((unsigned)q.x >> 24);
        int pos = base_p + atomicAdd(&lrun[lr], 1);
        pairs[pos] = make_int2(q.x & 0xFFFFFF, q.y);
    }
}

// ---------------------------------------------------------------------------
// MFMA transform: dst_bf16[n,64] = src_f32[n,64] @ W^T
struct XfArgs {
    const float* src[3];
    const unsigned short* wbf[3];
    unsigned short* dst[3];
    int n[3];
    int base[4];
};
__global__ __launch_bounds__(256) void xform_mfma(XfArgs a) {
    int b = blockIdx.x;
    int si = (b >= a.base[1]) + (b >= a.base[2]);
    const float* src = a.src[si];
    const unsigned short* wb = a.wbf[si];
    unsigned short* dst = a.dst[si];
    const int n = a.n[si];

    const int lane = threadIdx.x & 63;
    const int wv   = threadIdx.x >> 6;
    const int rbw  = (b - a.base[si]) * 64 + wv * 16;
    const int m = lane & 15, g = lane >> 4;

    f32x4 acc0 = {0.f, 0.f, 0.f, 0.f};
    f32x4 acc1 = acc0, acc2 = acc0, acc3 = acc0;

    const int arow = min(rbw + m, n - 1);
    const float* xp = src + (size_t)arow * D + g * 8;
    const unsigned short* wp0 = wb + (size_t)m * D + g * 8;

    #pragma unroll
    for (int t = 0; t < 2; ++t) {
        float4 a0 = *(const float4*)(xp + t * 32);
        float4 a1 = *(const float4*)(xp + t * 32 + 4);
        short8 af;
        af[0] = (short)f2bf(a0.x); af[1] = (short)f2bf(a0.y);
        af[2] = (short)f2bf(a0.z); af[3] = (short)f2bf(a0.w);
        af[4] = (short)f2bf(a1.x); af[5] = (short)f2bf(a1.y);
        af[6] = (short)f2bf(a1.z); af[7] = (short)f2bf(a1.w);
        const unsigned short* wp = wp0 + t * 32;
        short8 b0 = *(const short8*)(wp);
        short8 b1 = *(const short8*)(wp + 16 * D);
        short8 b2 = *(const short8*)(wp + 32 * D);
        short8 b3 = *(const short8*)(wp + 48 * D);
        acc0 = __builtin_amdgcn_mfma_f32_16x16x32_bf16(af, b0, acc0, 0, 0, 0);
        acc1 = __builtin_amdgcn_mfma_f32_16x16x32_bf16(af, b1, acc1, 0, 0, 0);
        acc2 = __builtin_amdgcn_mfma_f32_16x16x32_bf16(af, b2, acc2, 0, 0, 0);
        acc3 = __builtin_amdgcn_mfma_f32_16x16x32_bf16(af, b3, acc3, 0, 0, 0);
    }

    #pragma unroll
    for (int reg = 0; reg < 4; ++reg) {
        int orow = rbw + g * 4 + reg;
        if (orow < n) {
            size_t o = (size_t)orow * D + m;
            dst[o]      = f2bf(acc0[reg]);
            dst[o + 16] = f2bf(acc1[reg]);
            dst[o + 32] = f2bf(acc2[reg]);
            dst[o + 48] = f2bf(acc3[reg]);
        }
    }
}

// ---------------------------------------------------------------------------
// SpMM + epilogue, round-10 structure: block = 256 thr = 4 waves; each wave
// handles 4 rows via 16-lane groups (unroll-4 gather => 16 outstanding
// segments/wave). NEXT: block's 16 LN rows staged in LDS; the 4 waves then
// compute Ynext = LNout @ Wnext^T (wave wv -> output cols wv*16..+15).
struct SpArgs {
    const int* rptr[3];
    const int2* pairs[3];
    const unsigned short* y[3];
    const float* cur[3];
    const float* bias[3];
    const float* gamma[3];
    const float* beta[3];
    float* dst[3];
    const unsigned short* wnext[3];
    unsigned short* ynext[3];
    int n[3];
    int nnzc[3];
    int base[4];
};
template<int NEXT>
__global__ __launch_bounds__(256) void spmm_ln(SpArgs a) {
    __shared__ float lno[16][68];
    int b = blockIdx.x;
    int si = (b >= a.base[1]) + (b >= a.base[2]);
    const int lb = b - a.base[si];
    const int* rptr = a.rptr[si];
    const int2* pairs = a.pairs[si];
    const unsigned short* y = a.y[si];

    const int lane = threadIdx.x & 63;
    const int wv   = threadIdx.x >> 6;
    const int r = lane >> 4, sub = lane & 15;
    const int rib = wv * 4 + r;                 // row in block (0..15)
    const int row = lb * 16 + rib;

    const int start = rptr[row];
    const int end   = (row == a.n[si] - 1) ? a.nnzc[si] : rptr[row + 1];

    float4 acc  = make_float4(0.f, 0.f, 0.f, 0.f);
    float4 acc2 = make_float4(0.f, 0.f, 0.f, 0.f);
    int e = start;
    for (; e + 4 <= end; e += 4) {
        int2 p0 = pairs[e];
        int2 p1 = pairs[e + 1];
        int2 p2 = pairs[e + 2];
        int2 p3 = pairs[e + 3];
        float v0 = __int_as_float(p0.y);
        float v1 = __int_as_float(p1.y);
        float v2 = __int_as_float(p2.y);
        float v3 = __int_as_float(p3.y);
        ushort4 q0 = *(const ushort4*)(y + (size_t)p0.x * D + sub * 4);
        ushort4 q1 = *(const ushort4*)(y + (size_t)p1.x * D + sub * 4);
        ushort4 q2 = *(const ushort4*)(y + (size_t)p2.x * D + sub * 4);
        ushort4 q3 = *(const ushort4*)(y + (size_t)p3.x * D + sub * 4);
        acc.x  += v0 * bf2f(q0.x); acc.y  += v0 * bf2f(q0.y);
        acc.z  += v0 * bf2f(q0.z); acc.w  += v0 * bf2f(q0.w);
        acc2.x += v1 * bf2f(q1.x); acc2.y += v1 * bf2f(q1.y);
        acc2.z += v1 * bf2f(q1.z); acc2.w += v1 * bf2f(q1.w);
        acc.x  += v2 * bf2f(q2.x); acc.y  += v2 * bf2f(q2.y);
        acc.z  += v2 * bf2f(q2.z); acc.w  += v2 * bf2f(q2.w);
        acc2.x += v3 * bf2f(q3.x); acc2.y += v3 * bf2f(q3.y);
        acc2.z += v3 * bf2f(q3.z); acc2.w += v3 * bf2f(q3.w);
    }
    for (; e < end; ++e) {
        int2 p0 = pairs[e];
        float v0 = __int_as_float(p0.y);
        ushort4 q0 = *(const ushort4*)(y + (size_t)p0.x * D + sub * 4);
        acc.x += v0 * bf2f(q0.x); acc.y += v0 * bf2f(q0.y);
        acc.z += v0 * bf2f(q0.z); acc.w += v0 * bf2f(q0.w);
    }
    acc.x += acc2.x; acc.y += acc2.y; acc.z += acc2.z; acc.w += acc2.w;

    float4 bi = *(const float4*)(a.bias[si] + sub * 4);
    float4 h;
    h.x = acc.x + bi.x; h.y = acc.y + bi.y; h.z = acc.z + bi.z; h.w = acc.w + bi.w;
    h.x = h.x > 0.f ? h.x : LSLOPE * h.x;
    h.y = h.y > 0.f ? h.y : LSLOPE * h.y;
    h.z = h.z > 0.f ? h.z : LSLOPE * h.z;
    h.w = h.w > 0.f ? h.w : LSLOPE * h.w;
    float4 cu = *(const float4*)(a.cur[si] + (size_t)row * D + sub * 4);
    float4 x;
    x.x = cu.x + h.x; x.y = cu.y + h.y; x.z = cu.z + h.z; x.w = cu.w + h.w;

    float s  = x.x + x.y + x.z + x.w;
    float s2 = x.x * x.x + x.y * x.y + x.z * x.z + x.w * x.w;
    #pragma unroll
    for (int m = 8; m >= 1; m >>= 1) {
        s  += __shfl_xor(s, m, 64);
        s2 += __shfl_xor(s2, m, 64);
    }
    float mean = s * (1.f / 64.f);
    float var  = s2 * (1.f / 64.f) - mean * mean;
    float rstd = rsqrtf(var + LN_EPS);

    float4 g4  = *(const float4*)(a.gamma[si] + sub * 4);
    float4 be4 = *(const float4*)(a.beta[si]  + sub * 4);
    float4 o;
    o.x = (x.x - mean) * rstd * g4.x + be4.x;
    o.y = (x.y - mean) * rstd * g4.y + be4.y;
    o.z = (x.z - mean) * rstd * g4.z + be4.z;
    o.w = (x.w - mean) * rstd * g4.w + be4.w;
    *(float4*)(a.dst[si] + (size_t)row * D + sub * 4) = o;

    if (NEXT) {
        *(float4*)&lno[rib][sub * 4] = o;
        __syncthreads();
        // wave wv computes Ynext cols wv*16..wv*16+15 for the block's 16 rows
        const unsigned short* wn = a.wnext[si];
        unsigned short* yn = a.ynext[si] + (size_t)(lb * 16) * D;
        const int m = lane & 15, g = lane >> 4;
        f32x4 c = {0.f, 0.f, 0.f, 0.f};
        #pragma unroll
        for (int t = 0; t < 2; ++t) {
            float4 a0 = *(const float4*)&lno[m][t * 32 + g * 8];
            float4 a1 = *(const float4*)&lno[m][t * 32 + g * 8 + 4];
            short8 af;
            af[0] = (short)f2bf(a0.x); af[1] = (short)f2bf(a0.y);
            af[2] = (short)f2bf(a0.z); af[3] = (short)f2bf(a0.w);
            af[4] = (short)f2bf(a1.x); af[5] = (short)f2bf(a1.y);
            af[6] = (short)f2bf(a1.z); af[7] = (short)f2bf(a1.w);
            short8 bf = *(const short8*)(wn + (size_t)(wv * 16 + m) * D + t * 32 + g * 8);
            c = __builtin_amdgcn_mfma_f32_16x16x32_bf16(af, bf, c, 0, 0, 0);
        }
        #pragma unroll
        for (int reg = 0; reg < 4; ++reg)
            yn[(size_t)(g * 4 + reg) * D + wv * 16 + m] = f2bf(c[reg]);
    }
}

// ---------------------------------------------------------------------------
extern "C" void kernel_launch(void* const* d_in, const int* in_sizes, int n_in,
                              void* d_out, int out_size, void* d_ws, size_t ws_size,
                              hipStream_t stream)
{
    const float* user_emb = (const float*)d_in[0];
    const float* item_emb = (const float*)d_in[1];
    const int*   ui_rows  = (const int*)d_in[2];
    const int*   ui_cols  = (const int*)d_in[3];
    const float* ui_vals  = (const float*)d_in[4];
    const int*   soc_rows = (const int*)d_in[5];
    const int*   soc_cols = (const int*)d_in[6];
    const float* soc_vals = (const float*)d_in[7];
    const float* ui_W     = (const float*)d_in[8];
    const float* ui_b     = (const float*)d_in[9];
    const float* soc_W    = (const float*)d_in[10];
    const float* soc_b    = (const float*)d_in[11];
    const float* ln_ui_g  = (const float*)d_in[12];
    const float* ln_ui_b  = (const float*)d_in[13];
    const float* ln_soc_g = (const float*)d_in[14];
    const float* ln_soc_b = (const float*)d_in[15];

    float* out = (float*)d_out;
    const size_t UD = (size_t)U_N * D;
    const size_t ID = (size_t)I_N * D;

    float* o_ui0 = out;
    float* o_ui1 = out + UD;
    float* o_ui2 = out + 2 * UD;
    float* o_s0  = out + 3 * UD;
    float* o_s1  = out + 4 * UD;
    float* o_s2  = out + 5 * UD;
    float* o_ci  = out + 6 * UD;

    // workspace layout
    int2* pairs_ui  = (int2*)d_ws;
    int2* pairs_uiT = pairs_ui + NNZ_UI;
    int2* pairs_soc = pairs_uiT + NNZ_UI;
    int*  rp_ui     = (int*)(pairs_soc + NNZ_SOC);
    int*  rp_uiT    = rp_ui + U_N;
    int*  rp_soc    = rp_uiT + I_N;
    int*  bsum      = rp_soc + U_N;
    unsigned short* wbf = (unsigned short*)(bsum + 512);
    unsigned short* Yi  = wbf + 16384;   // I*D bf16
    unsigned short* Yu  = Yi + ID;       // U*D
    unsigned short* Ys  = Yu + UD;       // U*D
    unsigned short* Yi2 = Ys + UD;       // second Y set (fused path only)
    unsigned short* Yu2 = Yi2 + ID;
    unsigned short* Ys2 = Yu2 + UD;
    // bucket copy + count matrices overlap the first Y region (dead before T0)
    int2* bkt_ui  = (int2*)Yi;
    int2* bkt_uiT = bkt_ui + NNZ_UI;
    int2* bkt_soc = bkt_uiT + NNZ_UI;
    int*  cnt_ui  = (int*)(bkt_soc + NNZ_SOC);
    int*  cnt_uiT = cnt_ui + NB_UI * NBLK_UI;
    int*  cnt_soc = cnt_uiT + NB_UIT * NBLK_UI;

    const unsigned short* wbfUI0 = wbf;
    const unsigned short* wbfUI1 = wbf + 4096;
    const unsigned short* wbfS0  = wbf + 8192;
    const unsigned short* wbfS1  = wbf + 12288;

    const bool fused = ws_size >= (size_t)((char*)(Ys2 + UD) - (char*)d_ws);

    const int nthr = 256;

    // 1) weights to bf16
    wbf_k<<<64, nthr, 0, stream>>>(ui_W, soc_W, wbf);

    // 2) Phase A: bucket counts
    {
        BCArgs ba;
        ba.rows4[0] = (const int4*)ui_rows;  ba.cnt[0] = cnt_ui;  ba.nnz[0] = NNZ_UI;
        ba.nblk[0] = NBLK_UI;  ba.nbuck[0] = NB_UI;
        ba.rows4[1] = (const int4*)ui_cols;  ba.cnt[1] = cnt_uiT; ba.nnz[1] = NNZ_UI;
        ba.nblk[1] = NBLK_UI;  ba.nbuck[1] = NB_UIT;
        ba.rows4[2] = (const int4*)soc_rows; ba.cnt[2] = cnt_soc; ba.nnz[2] = NNZ_SOC;
        ba.nblk[2] = NBLK_SOC; ba.nbuck[2] = NB_SOC;
        ba.base[0] = 0; ba.base[1] = NBLK_UI; ba.base[2] = 2 * NBLK_UI;
        ba.base[3] = 2 * NBLK_UI + NBLK_SOC;
        bucket_cnt<<<ba.base[3], nthr, 0, stream>>>(ba);
    }

    // 3) Phase B: scans
    {
        ScanArgs sa;
        sa.cnt[0] = cnt_ui;  sa.n[0] = NB_UI * NBLK_UI;
        sa.cnt[1] = cnt_uiT; sa.n[1] = NB_UIT * NBLK_UI;
        sa.cnt[2] = cnt_soc; sa.n[2] = NB_SOC * NBLK_SOC;
        int nb0 = (sa.n[0] + SCAN_CHUNK - 1) / SCAN_CHUNK;
        int nb1 = (sa.n[1] + SCAN_CHUNK - 1) / SCAN_CHUNK;
        int nb2 = (sa.n[2] + SCAN_CHUNK - 1) / SCAN_CHUNK;
        sa.nb[0] = nb0; sa.nb[1] = nb1; sa.nb[2] = nb2;
        sa.off[0] = 0; sa.off[1] = nb0; sa.off[2] = nb0 + nb1;
        sa.base[0] = 0; sa.base[1] = nb0; sa.base[2] = nb0 + nb1; sa.base[3] = nb0 + nb1 + nb2;
        scan_p1<<<sa.base[3], nthr, 0, stream>>>(sa, bsum);
        scan_p2<<<3, nthr, 0, stream>>>(sa, bsum);
        scan_p3<<<sa.base[3], nthr, 0, stream>>>(sa, bsum);
    }

    // 4) Phase C: bucket-grouped edge copy
    {
        BSArgs ca;
        ca.rows[0] = ui_rows;  ca.cols[0] = ui_cols;  ca.vals[0] = ui_vals;
        ca.cofs[0] = cnt_ui;  ca.bkt[0] = bkt_ui;  ca.nnz[0] = NNZ_UI;
        ca.nblk[0] = NBLK_UI;  ca.nbuck[0] = NB_UI;
        ca.rows[1] = ui_cols;  ca.cols[1] = ui_rows;  ca.vals[1] = ui_vals;
        ca.cofs[1] = cnt_uiT; ca.bkt[1] = bkt_uiT; ca.nnz[1] = NNZ_UI;
        ca.nblk[1] = NBLK_UI;  ca.nbuck[1] = NB_UIT;
        ca.rows[2] = soc_rows; ca.cols[2] = soc_cols; ca.vals[2] = soc_vals;
        ca.cofs[2] = cnt_soc; ca.bkt[2] = bkt_soc; ca.nnz[2] = NNZ_SOC;
        ca.nblk[2] = NBLK_SOC; ca.nbuck[2] = NB_SOC;
        ca.base[0] = 0; ca.base[1] = NBLK_UI; ca.base[2] = 2 * NBLK_UI;
        ca.base[3] = 2 * NBLK_UI + NBLK_SOC;
        bucket_scat<<<ca.base[3], nthr, 0, stream>>>(ca);
    }

    // 5) copy user_emb to output slots
    copy2_f4<<<(int)(UD / 4 + nthr - 1) / nthr, nthr, 0, stream>>>(
        (const float4*)user_emb, (float4*)o_ui0, (float4*)o_s0, (int)(UD / 4));

    // 6) Phase D: per-bucket CSR finalize
    {
        BDArgs da;
        da.cofs[0] = cnt_ui;  da.bkt[0] = bkt_ui;  da.pairs[0] = pairs_ui;  da.rp[0] = rp_ui;
        da.nnz[0] = NNZ_UI;  da.nblk[0] = NBLK_UI;  da.nbuck[0] = NB_UI;  da.nrows[0] = U_N;
        da.cofs[1] = cnt_uiT; da.bkt[1] = bkt_uiT; da.pairs[1] = pairs_uiT; da.rp[1] = rp_uiT;
        da.nnz[1] = NNZ_UI;  da.nblk[1] = NBLK_UI;  da.nbuck[1] = NB_UIT; da.nrows[1] = I_N;
        da.cofs[2] = cnt_soc; da.bkt[2] = bkt_soc; da.pairs[2] = pairs_soc; da.rp[2] = rp_soc;
        da.nnz[2] = NNZ_SOC; da.nblk[2] = NBLK_SOC; da.nbuck[2] = NB_SOC;  da.nrows[2] = U_N;
        da.base[0] = 0; da.base[1] = NB_UI; da.base[2] = NB_UI + NB_UIT;
        da.base[3] = NB_UI + NB_UIT + NB_SOC;
        bucket_csr<<<da.base[3], nthr, 0, stream>>>(da);
    }

    const int xb_i = (I_N + 63) / 64;
    const int xb_u = (U_N + 63) / 64;

    // 7) T0: layer-0 transforms of raw embeddings
    {
        XfArgs xa;
        xa.src[0] = item_emb; xa.wbf[0] = wbfUI0; xa.dst[0] = Yi; xa.n[0] = I_N;
        xa.src[1] = user_emb; xa.wbf[1] = wbfUI0; xa.dst[1] = Yu; xa.n[1] = U_N;
        xa.src[2] = user_emb; xa.wbf[2] = wbfS0;  xa.dst[2] = Ys; xa.n[2] = U_N;
        xa.base[0] = 0; xa.base[1] = xb_i; xa.base[2] = xb_i + xb_u; xa.base[3] = xb_i + 2 * xb_u;
        xform_mfma<<<xa.base[3], nthr, 0, stream>>>(xa);
    }

    // common SpArgs skeleton
    SpArgs p0;
    p0.rptr[0] = rp_ui;  p0.pairs[0] = pairs_ui;  p0.y[0] = Yi; p0.cur[0] = user_emb;
    p0.bias[0] = ui_b;  p0.gamma[0] = ln_ui_g;  p0.beta[0] = ln_ui_b;  p0.dst[0] = o_ui1;
    p0.n[0] = U_N; p0.nnzc[0] = NNZ_UI;
    p0.rptr[1] = rp_uiT; p0.pairs[1] = pairs_uiT; p0.y[1] = Yu; p0.cur[1] = item_emb;
    p0.bias[1] = ui_b;  p0.gamma[1] = ln_ui_g;  p0.beta[1] = ln_ui_b;  p0.dst[1] = o_ci;
    p0.n[1] = I_N; p0.nnzc[1] = NNZ_UI;
    p0.rptr[2] = rp_soc; p0.pairs[2] = pairs_soc; p0.y[2] = Ys; p0.cur[2] = user_emb;
    p0.bias[2] = soc_b; p0.gamma[2] = ln_soc_g; p0.beta[2] = ln_soc_b; p0.dst[2] = o_s1;
    p0.n[2] = U_N; p0.nnzc[2] = NNZ_SOC;
    p0.base[0] = 0; p0.base[1] = U_N / 16; p0.base[2] = U_N / 16 + I_N / 16;
    p0.base[3] = 2 * (U_N / 16) + I_N / 16;
    p0.wnext[0] = nullptr; p0.wnext[1] = nullptr; p0.wnext[2] = nullptr;
    p0.ynext[0] = nullptr; p0.ynext[1] = nullptr; p0.ynext[2] = nullptr;

    SpArgs p1 = p0;
    p1.bias[0] = ui_b + 64;  p1.gamma[0] = ln_ui_g + 64;  p1.beta[0] = ln_ui_b + 64;
    p1.bias[1] = ui_b + 64;  p1.gamma[1] = ln_ui_g + 64;  p1.beta[1] = ln_ui_b + 64;
    p1.bias[2] = soc_b + 64; p1.gamma[2] = ln_soc_g + 64; p1.beta[2] = ln_soc_b + 64;
    p1.cur[0] = o_ui1; p1.dst[0] = o_ui2;
    p1.cur[1] = o_ci;  p1.dst[1] = o_ci;   // in-place: row read then written by same thread
    p1.cur[2] = o_s1;  p1.dst[2] = o_s2;

    if (fused) {
        // 8) spmm L0 with fused next-layer transform:
        //    sec0 outputs users -> Yu2; sec1 outputs items -> Yi2; sec2 -> Ys2
        p0.wnext[0] = wbfUI1; p0.ynext[0] = Yu2;
        p0.wnext[1] = wbfUI1; p0.ynext[1] = Yi2;
        p0.wnext[2] = wbfS1;  p0.ynext[2] = Ys2;
        spmm_ln<1><<<p0.base[3], nthr, 0, stream>>>(p0);

        // 9) spmm L1 gathers from second Y set
        p1.y[0] = Yi2; p1.y[1] = Yu2; p1.y[2] = Ys2;
        spmm_ln<0><<<p1.base[3], nthr, 0, stream>>>(p1);
    } else {
        // fallback: round-10 sequence (separate T1)
        spmm_ln<0><<<p0.base[3], nthr, 0, stream>>>(p0);
        {
            XfArgs xa;
            xa.src[0] = o_ci;  xa.wbf[0] = wbfUI1; xa.dst[0] = Yi; xa.n[0] = I_N;
            xa.src[1] = o_ui1; xa.wbf[1] = wbfUI1; xa.dst[1] = Yu; xa.n[1] = U_N;
            xa.src[2] = o_s1;  xa.wbf[2] = wbfS1;  xa.dst[2] = Ys; xa.n[2] = U_N;
            xa.base[0] = 0; xa.base[1] = xb_i; xa.base[2] = xb_i + xb_u;
            xa.base[3] = xb_i + 2 * xb_u;
            xform_mfma<<<xa.base[3], nthr, 0, stream>>>(xa);
        }
        spmm_ln<0><<<p1.base[3], nthr, 0, stream>>>(p1);
    }
}